// Round 3
// baseline (174.440 us; speedup 1.0000x reference)
//
#include <hip/hip_runtime.h>
#include <hip/hip_bf16.h>

// Self-guided-filter loss, fused per 32x32 tile. v3: minimize wave-level LDS ops.
// (8,3,512,512) fp32, RADIUS=5 (k=11), EPS=1e-6.
//
// P2: global -> h1 (horizontal 11-sums of x, x^2), vectorized.
// P4: vertical 11-sums over h1 -> a,b. ONE wave (44 tasks), h1x window in regs.
// P6: horizontal 11-sums of a,b -> h2a,h2b.
// P7: vertical 11-sums over h2 -> f; flit state in REGISTERS across images.
// Deterministic two-kernel reduction.

#define W 512
#define TB 32
#define H1STR 48   // h1: 52 rows, cols 0..41 valid (writes pad to 47)
#define ABSTR 44   // A,B: 42 rows, cols 0..43 written (0..41 meaningful)
#define H2STR 36   // h2: 42 rows, cols 0..31

#define O_H1X 0
#define O_H1Y 2496
#define O_A   4992
#define O_B   6840
#define O_H2A 0      // aliases h1x (dead after P4)
#define O_H2B 2496   // aliases h1y
#define S_FLOATS 8688  // 34,752 B -> 4 blocks/CU

#define NBLK_X 16
#define NBLK_Y 16
#define NPLANES 24
#define NPARTIALS (NBLK_X*NBLK_Y*NPLANES)
#define TOTAL_ELEMS 6291456.0
#define INV121 (1.0f/121.0f)

__device__ __forceinline__ float4 ld4(const float* p) { return *(const float4*)p; }

__global__ __launch_bounds__(256, 4) void sgf_loss_kernel(
    const float* __restrict__ gen, const float* __restrict__ ir,
    const float* __restrict__ vi, float* __restrict__ partials)
{
    __shared__ __align__(16) float S[S_FLOATS];
    const int tid = threadIdx.x;
    const int tx0 = blockIdx.x * TB;
    const int ty0 = blockIdx.y * TB;
    const size_t pbase = (size_t)blockIdx.z * (W * W);

    float acc = 0.0f;
    float fst[4][4];   // flit state, lanes tid<64 only (static indices -> regs)

    #pragma unroll 1
    for (int img = 0; img < 3; ++img) {
        const float* __restrict__ X =
            (img == 0 ? ir : (img == 1 ? vi : gen)) + pbase;

        __syncthreads();   // h1 region was read (as h2) in previous image's P7

        // ---- P2: global -> h1 horizontal 11-sums of x and x^2.
        // 312 tasks: 52 rows x 6 col-groups of 8. h1 col j window = img cols tx0-10+j..tx0+j.
        for (int t = tid; t < 312; t += 256) {
            int r = t / 6, cg = t - r * 6;
            int j0 = cg * 8;
            float* hx = &S[O_H1X + r * H1STR + j0];
            float* hy = &S[O_H1Y + r * H1STR + j0];
            int gy = ty0 - 10 + r;
            if ((unsigned)gy >= (unsigned)W) {
                float4 z = make_float4(0.f, 0.f, 0.f, 0.f);
                *(float4*)hx = z; *(float4*)(hx + 4) = z;
                *(float4*)hy = z; *(float4*)(hy + 4) = z;
                continue;
            }
            const float* Xr = X + (size_t)gy * W;
            int gx0 = tx0 - 12 + j0;           // 16B-aligned (tx0%32==0)
            float w[20];
            if (gx0 >= 0 && gx0 + 20 <= W) {
                const float4* p = (const float4*)(Xr + gx0);
                float4 v0 = p[0], v1 = p[1], v2 = p[2], v3 = p[3], v4 = p[4];
                w[0]=v0.x;  w[1]=v0.y;  w[2]=v0.z;  w[3]=v0.w;
                w[4]=v1.x;  w[5]=v1.y;  w[6]=v1.z;  w[7]=v1.w;
                w[8]=v2.x;  w[9]=v2.y;  w[10]=v2.z; w[11]=v2.w;
                w[12]=v3.x; w[13]=v3.y; w[14]=v3.z; w[15]=v3.w;
                w[16]=v4.x; w[17]=v4.y; w[18]=v4.z; w[19]=v4.w;
            } else {
                #pragma unroll
                for (int k = 0; k < 20; ++k) {
                    int gx = gx0 + k;
                    w[k] = ((unsigned)gx < (unsigned)W) ? Xr[gx] : 0.f;
                }
            }
            float o[8], u[8];
            float s = w[2]+w[3]+w[4]+w[5]+w[6]+w[7]+w[8]+w[9]+w[10]+w[11]+w[12];
            o[0] = s;
            #pragma unroll
            for (int k = 1; k < 8; ++k) { s += w[12+k] - w[1+k]; o[k] = s; }
            float sq[20];
            #pragma unroll
            for (int k = 2; k < 20; ++k) sq[k] = w[k] * w[k];
            float s2 = sq[2]+sq[3]+sq[4]+sq[5]+sq[6]+sq[7]+sq[8]+sq[9]+sq[10]+sq[11]+sq[12];
            u[0] = s2;
            #pragma unroll
            for (int k = 1; k < 8; ++k) { s2 += sq[12+k] - sq[1+k]; u[k] = s2; }
            *(float4*)hx       = make_float4(o[0], o[1], o[2], o[3]);
            *(float4*)(hx + 4) = make_float4(o[4], o[5], o[6], o[7]);
            *(float4*)hy       = make_float4(u[0], u[1], u[2], u[3]);
            *(float4*)(hy + 4) = make_float4(u[4], u[5], u[6], u[7]);
        }
        __syncthreads();

        // ---- P4/5: vertical 11-sums over h1 + pointwise a,b. 44 tasks (ONE wave):
        // cg 0..10 (cols 4cg..4cg+3), chunk 0..3 -> rows {0..10,11..21,22..31,32..41}.
        if (tid < 44) {
            int chunk = tid / 11, cg = tid - chunk * 11;
            int r0 = chunk * 11 - (chunk == 3 ? 1 : 0);   // 0,11,22,32
            int L  = (chunk >= 2) ? 10 : 11;
            int c4 = cg * 4;
            float mv[4];   // col mask folded into 1/121
            #pragma unroll
            for (int k = 0; k < 4; ++k) {
                int gx = tx0 - 5 + c4 + k;
                mv[k] = ((unsigned)gx < (unsigned)W) ? INV121 : 0.0f;
            }
            const float* hx = &S[O_H1X + c4];
            const float* hy = &S[O_H1Y + c4];
            float4 win[11];
            float sx0=0,sx1=0,sx2=0,sx3=0, sy0=0,sy1=0,sy2=0,sy3=0;
            #pragma unroll
            for (int d = 0; d < 10; ++d) {
                float4 xn = ld4(hx + (r0 + d) * H1STR);
                float4 yn = ld4(hy + (r0 + d) * H1STR);
                win[d] = xn;
                sx0+=xn.x; sx1+=xn.y; sx2+=xn.z; sx3+=xn.w;
                sy0+=yn.x; sy1+=yn.y; sy2+=yn.z; sy3+=yn.w;
            }
            #pragma unroll
            for (int j = 0; j < 11; ++j) {
                int rr = r0 + 10 + j; if (rr > 51) rr = 51;   // clamp (masked anyway)
                float4 xn = ld4(hx + rr * H1STR);
                float4 yn = ld4(hy + rr * H1STR);
                if (j == 0) win[10] = xn;
                sx0+=xn.x; sx1+=xn.y; sx2+=xn.z; sx3+=xn.w;
                sy0+=yn.x; sy1+=yn.y; sy2+=yn.z; sy3+=yn.w;
                if (j < L) {
                    int q = r0 + j;
                    int gy = ty0 - 5 + q;
                    float4 av, bv;
                    if ((unsigned)gy < (unsigned)W) {
                        float sxk[4] = {sx0, sx1, sx2, sx3};
                        float syk[4] = {sy0, sy1, sy2, sy3};
                        float ao[4], bo[4];
                        #pragma unroll
                        for (int k = 0; k < 4; ++k) {
                            float mean = sxk[k] * mv[k];
                            float corr = syk[k] * mv[k];
                            float var  = fmaf(-mean, mean, corr);
                            float a_   = var * __builtin_amdgcn_rcpf(var + 1e-6f);
                            ao[k] = a_;
                            bo[k] = fmaf(-a_, mean, mean);
                        }
                        av = make_float4(ao[0], ao[1], ao[2], ao[3]);
                        bv = make_float4(bo[0], bo[1], bo[2], bo[3]);
                    } else {
                        av = make_float4(0.f,0.f,0.f,0.f); bv = av;
                    }
                    *(float4*)&S[O_A + q * ABSTR + c4] = av;
                    *(float4*)&S[O_B + q * ABSTR + c4] = bv;
                    // slide: x window from regs, y oldest re-read from LDS
                    float4 xo = win[j];
                    sx0-=xo.x; sx1-=xo.y; sx2-=xo.z; sx3-=xo.w;
                    float4 yo = ld4(hy + q * H1STR);
                    sy0-=yo.x; sy1-=yo.y; sy2-=yo.z; sy3-=yo.w;
                }
            }
        }
        __syncthreads();

        // ---- P6: horizontal 11-sums of a,b -> h2a,h2b. 168 tasks (r 0..41, cg 0..3 -> 8 cols).
        if (tid < 168) {
            int r = tid >> 2, cg = tid & 3;
            int j0 = cg * 8;
            const float* Ap = &S[O_A + r * ABSTR + j0];
            const float* Bp = &S[O_B + r * ABSTR + j0];
            float wa[20], wb[20];
            #pragma unroll
            for (int k = 0; k < 5; ++k) {
                float4 va = ld4(Ap + 4 * k);
                wa[4*k]=va.x; wa[4*k+1]=va.y; wa[4*k+2]=va.z; wa[4*k+3]=va.w;
                float4 vb = ld4(Bp + 4 * k);
                wb[4*k]=vb.x; wb[4*k+1]=vb.y; wb[4*k+2]=vb.z; wb[4*k+3]=vb.w;
            }
            float oa[8], ob[8];
            float s = wa[0]+wa[1]+wa[2]+wa[3]+wa[4]+wa[5]+wa[6]+wa[7]+wa[8]+wa[9]+wa[10];
            oa[0] = s;
            #pragma unroll
            for (int k = 1; k < 8; ++k) { s += wa[10+k] - wa[k-1]; oa[k] = s; }
            float s2 = wb[0]+wb[1]+wb[2]+wb[3]+wb[4]+wb[5]+wb[6]+wb[7]+wb[8]+wb[9]+wb[10];
            ob[0] = s2;
            #pragma unroll
            for (int k = 1; k < 8; ++k) { s2 += wb[10+k] - wb[k-1]; ob[k] = s2; }
            float* da = &S[O_H2A + r * H2STR + j0];
            float* db = &S[O_H2B + r * H2STR + j0];
            *(float4*)da       = make_float4(oa[0], oa[1], oa[2], oa[3]);
            *(float4*)(da + 4) = make_float4(oa[4], oa[5], oa[6], oa[7]);
            *(float4*)db       = make_float4(ob[0], ob[1], ob[2], ob[3]);
            *(float4*)(db + 4) = make_float4(ob[4], ob[5], ob[6], ob[7]);
        }
        __syncthreads();

        // ---- P7/8: vertical 11-sums over h2 -> f; flit in regs. 64 tasks (ONE wave):
        // cg 0..7 (cols 4cg), chunk 0..7 (rows 4*chunk..4*chunk+3).
        if (tid < 64) {
            int chunk = tid >> 3, cg = tid & 7;
            int r0 = chunk * 4, c4 = cg * 4;
            const float* ha = &S[O_H2A + c4];
            const float* hb = &S[O_H2B + c4];
            float sa[4] = {0,0,0,0}, sb[4] = {0,0,0,0};
            #pragma unroll
            for (int d = 0; d < 10; ++d) {
                float4 a = ld4(ha + (r0 + d) * H2STR);
                float4 b = ld4(hb + (r0 + d) * H2STR);
                sa[0]+=a.x; sa[1]+=a.y; sa[2]+=a.z; sa[3]+=a.w;
                sb[0]+=b.x; sb[1]+=b.y; sb[2]+=b.z; sb[3]+=b.w;
            }
            #pragma unroll
            for (int j = 0; j < 4; ++j) {
                int q = r0 + j;
                {
                    float4 a = ld4(ha + (q + 10) * H2STR);
                    float4 b = ld4(hb + (q + 10) * H2STR);
                    sa[0]+=a.x; sa[1]+=a.y; sa[2]+=a.z; sa[3]+=a.w;
                    sb[0]+=b.x; sb[1]+=b.y; sb[2]+=b.z; sb[3]+=b.w;
                }
                float4 xv = ld4(X + (size_t)(ty0 + q) * W + (tx0 + c4));
                float xs[4] = {xv.x, xv.y, xv.z, xv.w};
                #pragma unroll
                for (int k = 0; k < 4; ++k) {
                    float t = fmaf(sa[k], xs[k], sb[k]);   // (boxa*x+boxb)*121
                    float f = fmaf(-t, INV121, xs[k]);     // x - q
                    if (img == 0)      fst[j][k] = fabsf(f);
                    else if (img == 1) fst[j][k] = fmaxf(fst[j][k], fabsf(f));
                    else               acc += fabsf(f - fst[j][k]);
                }
                {
                    float4 a = ld4(ha + q * H2STR);
                    float4 b = ld4(hb + q * H2STR);
                    sa[0]-=a.x; sa[1]-=a.y; sa[2]-=a.z; sa[3]-=a.w;
                    sb[0]-=b.x; sb[1]-=b.y; sb[2]-=b.z; sb[3]-=b.w;
                }
            }
        }
    } // img loop

    // acc nonzero only in wave 0: shuffle-reduce, lane 0 writes
    #pragma unroll
    for (int off = 32; off > 0; off >>= 1) acc += __shfl_down(acc, off);
    if (tid == 0)
        partials[((blockIdx.z * NBLK_Y) + blockIdx.y) * NBLK_X + blockIdx.x] = acc;
}

__global__ __launch_bounds__(256) void sgf_final_reduce(
    const float* __restrict__ partials, float* __restrict__ out)
{
    __shared__ double sd[256];
    int tid = threadIdx.x;
    double s = 0.0;
    for (int i = tid; i < NPARTIALS; i += 256) s += (double)partials[i];
    sd[tid] = s;
    __syncthreads();
    for (int off = 128; off > 0; off >>= 1) {
        if (tid < off) sd[tid] += sd[tid + off];
        __syncthreads();
    }
    if (tid == 0) out[0] = (float)(sd[0] * (1.0 / TOTAL_ELEMS));
}

extern "C" void kernel_launch(void* const* d_in, const int* in_sizes, int n_in,
                              void* d_out, int out_size, void* d_ws, size_t ws_size,
                              hipStream_t stream) {
    const float* gen = (const float*)d_in[0];
    const float* ir  = (const float*)d_in[1];
    const float* vi  = (const float*)d_in[2];
    float* partials = (float*)d_ws;   // 6144 floats = 24 KB

    dim3 grid(NBLK_X, NBLK_Y, NPLANES);
    sgf_loss_kernel<<<grid, dim3(256), 0, stream>>>(gen, ir, vi, partials);
    sgf_final_reduce<<<1, dim3(256), 0, stream>>>(partials, (float*)d_out);
}

// Round 4
// 169.235 us; speedup vs baseline: 1.0308x; 1.0308x over previous
//
#include <hip/hip_runtime.h>
#include <hip/hip_bf16.h>

// Self-guided-filter loss, fused per 32x32 tile. v4 = v3 minus the scratch spill:
// P4's register window removed (oldest-row re-read from LDS), flit stays in regs.
// (8,3,512,512) fp32, RADIUS=5 (k=11), EPS=1e-6.
//
// P2: global -> h1 (horizontal 11-sums of x, x^2), vectorized b128.
// P4: vertical 11-sums over h1 -> a,b. ONE wave (44 tasks), pure LDS sliding sums.
// P6: horizontal 11-sums of a,b -> h2a,h2b.
// P7: vertical 11-sums over h2 -> f; flit state in registers (static indices).
// Deterministic two-kernel reduction.

#define W 512
#define TB 32
#define H1STR 48   // h1: 52 rows, cols 0..41 valid
#define ABSTR 44   // A,B: 42 rows, cols 0..41 valid
#define H2STR 36   // h2: 42 rows, cols 0..31

#define O_H1X 0
#define O_H1Y 2496
#define O_A   4992
#define O_B   6840
#define O_H2A 0      // aliases h1x (dead after P4)
#define O_H2B 2496   // aliases h1y
#define S_FLOATS 8688  // 34,752 B -> 4 blocks/CU

#define NBLK_X 16
#define NBLK_Y 16
#define NPLANES 24
#define NPARTIALS (NBLK_X*NBLK_Y*NPLANES)
#define TOTAL_ELEMS 6291456.0
#define INV121 (1.0f/121.0f)

__device__ __forceinline__ float4 ld4(const float* p) { return *(const float4*)p; }

__global__ __launch_bounds__(256, 4) void sgf_loss_kernel(
    const float* __restrict__ gen, const float* __restrict__ ir,
    const float* __restrict__ vi, float* __restrict__ partials)
{
    __shared__ __align__(16) float S[S_FLOATS];
    const int tid = threadIdx.x;
    const int tx0 = blockIdx.x * TB;
    const int ty0 = blockIdx.y * TB;
    const size_t pbase = (size_t)blockIdx.z * (W * W);

    float acc = 0.0f;
    float fst[16];   // flit state (lanes tid<64); all indices compile-time static

    #pragma unroll 1
    for (int img = 0; img < 3; ++img) {
        const float* __restrict__ X =
            (img == 0 ? ir : (img == 1 ? vi : gen)) + pbase;

        __syncthreads();   // h1 region was read (as h2) in previous image's P7

        // ---- P2: global -> h1 horizontal 11-sums of x and x^2.
        // 312 tasks: 52 rows x 6 col-groups of 8. h1 col j window = img cols tx0-10+j..tx0+j.
        for (int t = tid; t < 312; t += 256) {
            int r = t / 6, cg = t - r * 6;
            int j0 = cg * 8;
            float* hx = &S[O_H1X + r * H1STR + j0];
            float* hy = &S[O_H1Y + r * H1STR + j0];
            int gy = ty0 - 10 + r;
            if ((unsigned)gy >= (unsigned)W) {
                float4 z = make_float4(0.f, 0.f, 0.f, 0.f);
                *(float4*)hx = z; *(float4*)(hx + 4) = z;
                *(float4*)hy = z; *(float4*)(hy + 4) = z;
                continue;
            }
            const float* Xr = X + (size_t)gy * W;
            int gx0 = tx0 - 12 + j0;           // 16B-aligned (tx0%32==0)
            float w[20];
            if (gx0 >= 0 && gx0 + 20 <= W) {
                const float4* p = (const float4*)(Xr + gx0);
                float4 v0 = p[0], v1 = p[1], v2 = p[2], v3 = p[3], v4 = p[4];
                w[0]=v0.x;  w[1]=v0.y;  w[2]=v0.z;  w[3]=v0.w;
                w[4]=v1.x;  w[5]=v1.y;  w[6]=v1.z;  w[7]=v1.w;
                w[8]=v2.x;  w[9]=v2.y;  w[10]=v2.z; w[11]=v2.w;
                w[12]=v3.x; w[13]=v3.y; w[14]=v3.z; w[15]=v3.w;
                w[16]=v4.x; w[17]=v4.y; w[18]=v4.z; w[19]=v4.w;
            } else {
                #pragma unroll
                for (int k = 0; k < 20; ++k) {
                    int gx = gx0 + k;
                    w[k] = ((unsigned)gx < (unsigned)W) ? Xr[gx] : 0.f;
                }
            }
            float o[8], u[8];
            float s = w[2]+w[3]+w[4]+w[5]+w[6]+w[7]+w[8]+w[9]+w[10]+w[11]+w[12];
            o[0] = s;
            #pragma unroll
            for (int k = 1; k < 8; ++k) { s += w[12+k] - w[1+k]; o[k] = s; }
            float sq[20];
            #pragma unroll
            for (int k = 2; k < 20; ++k) sq[k] = w[k] * w[k];
            float s2 = sq[2]+sq[3]+sq[4]+sq[5]+sq[6]+sq[7]+sq[8]+sq[9]+sq[10]+sq[11]+sq[12];
            u[0] = s2;
            #pragma unroll
            for (int k = 1; k < 8; ++k) { s2 += sq[12+k] - sq[1+k]; u[k] = s2; }
            *(float4*)hx       = make_float4(o[0], o[1], o[2], o[3]);
            *(float4*)(hx + 4) = make_float4(o[4], o[5], o[6], o[7]);
            *(float4*)hy       = make_float4(u[0], u[1], u[2], u[3]);
            *(float4*)(hy + 4) = make_float4(u[4], u[5], u[6], u[7]);
        }
        __syncthreads();

        // ---- P4/5: vertical 11-sums over h1 + pointwise a,b. 44 tasks (ONE wave):
        // cg 0..10 (cols 4cg..4cg+3), chunk 0..3 -> rows {0..10,11..21,22..31,32..41}.
        // Pure LDS sliding sums (no register window -> no scratch).
        if (tid < 44) {
            int chunk = tid / 11, cg = tid - chunk * 11;
            int r0 = chunk * 11 - (chunk == 3 ? 1 : 0);   // 0,11,22,32
            int L  = (chunk >= 2) ? 10 : 11;
            int c4 = cg * 4;
            float mv[4];   // col mask folded into 1/121
            #pragma unroll
            for (int k = 0; k < 4; ++k) {
                int gx = tx0 - 5 + c4 + k;
                mv[k] = ((unsigned)gx < (unsigned)W) ? INV121 : 0.0f;
            }
            const float* hx = &S[O_H1X + c4];
            const float* hy = &S[O_H1Y + c4];
            float sx0=0,sx1=0,sx2=0,sx3=0, sy0=0,sy1=0,sy2=0,sy3=0;
            #pragma unroll
            for (int d = 0; d < 10; ++d) {
                float4 xn = ld4(hx + (r0 + d) * H1STR);
                float4 yn = ld4(hy + (r0 + d) * H1STR);
                sx0+=xn.x; sx1+=xn.y; sx2+=xn.z; sx3+=xn.w;
                sy0+=yn.x; sy1+=yn.y; sy2+=yn.z; sy3+=yn.w;
            }
            for (int j = 0; j < L; ++j) {
                int q = r0 + j;
                {
                    float4 xn = ld4(hx + (q + 10) * H1STR);
                    float4 yn = ld4(hy + (q + 10) * H1STR);
                    sx0+=xn.x; sx1+=xn.y; sx2+=xn.z; sx3+=xn.w;
                    sy0+=yn.x; sy1+=yn.y; sy2+=yn.z; sy3+=yn.w;
                }
                int gy = ty0 - 5 + q;
                float4 av, bv;
                if ((unsigned)gy < (unsigned)W) {
                    float sxk[4] = {sx0, sx1, sx2, sx3};
                    float syk[4] = {sy0, sy1, sy2, sy3};
                    float ao[4], bo[4];
                    #pragma unroll
                    for (int k = 0; k < 4; ++k) {
                        float mean = sxk[k] * mv[k];
                        float corr = syk[k] * mv[k];
                        float var  = fmaf(-mean, mean, corr);
                        float a_   = var * __builtin_amdgcn_rcpf(var + 1e-6f);
                        ao[k] = a_;
                        bo[k] = fmaf(-a_, mean, mean);
                    }
                    av = make_float4(ao[0], ao[1], ao[2], ao[3]);
                    bv = make_float4(bo[0], bo[1], bo[2], bo[3]);
                } else {
                    av = make_float4(0.f,0.f,0.f,0.f); bv = av;
                }
                *(float4*)&S[O_A + q * ABSTR + c4] = av;
                *(float4*)&S[O_B + q * ABSTR + c4] = bv;
                {
                    float4 xo = ld4(hx + q * H1STR);
                    float4 yo = ld4(hy + q * H1STR);
                    sx0-=xo.x; sx1-=xo.y; sx2-=xo.z; sx3-=xo.w;
                    sy0-=yo.x; sy1-=yo.y; sy2-=yo.z; sy3-=yo.w;
                }
            }
        }
        __syncthreads();

        // ---- P6: horizontal 11-sums of a,b -> h2a,h2b. 168 tasks (r 0..41, cg 0..3 -> 8 cols).
        if (tid < 168) {
            int r = tid >> 2, cg = tid & 3;
            int j0 = cg * 8;
            const float* Ap = &S[O_A + r * ABSTR + j0];
            const float* Bp = &S[O_B + r * ABSTR + j0];
            float wa[20], wb[20];
            #pragma unroll
            for (int k = 0; k < 5; ++k) {
                float4 va = ld4(Ap + 4 * k);
                wa[4*k]=va.x; wa[4*k+1]=va.y; wa[4*k+2]=va.z; wa[4*k+3]=va.w;
                float4 vb = ld4(Bp + 4 * k);
                wb[4*k]=vb.x; wb[4*k+1]=vb.y; wb[4*k+2]=vb.z; wb[4*k+3]=vb.w;
            }
            float oa[8], ob[8];
            float s = wa[0]+wa[1]+wa[2]+wa[3]+wa[4]+wa[5]+wa[6]+wa[7]+wa[8]+wa[9]+wa[10];
            oa[0] = s;
            #pragma unroll
            for (int k = 1; k < 8; ++k) { s += wa[10+k] - wa[k-1]; oa[k] = s; }
            float s2 = wb[0]+wb[1]+wb[2]+wb[3]+wb[4]+wb[5]+wb[6]+wb[7]+wb[8]+wb[9]+wb[10];
            ob[0] = s2;
            #pragma unroll
            for (int k = 1; k < 8; ++k) { s2 += wb[10+k] - wb[k-1]; ob[k] = s2; }
            float* da = &S[O_H2A + r * H2STR + j0];
            float* db = &S[O_H2B + r * H2STR + j0];
            *(float4*)da       = make_float4(oa[0], oa[1], oa[2], oa[3]);
            *(float4*)(da + 4) = make_float4(oa[4], oa[5], oa[6], oa[7]);
            *(float4*)db       = make_float4(ob[0], ob[1], ob[2], ob[3]);
            *(float4*)(db + 4) = make_float4(ob[4], ob[5], ob[6], ob[7]);
        }
        __syncthreads();

        // ---- P7/8: vertical 11-sums over h2 -> f; flit in regs. 64 tasks (ONE wave):
        // cg 0..7 (cols 4cg), chunk 0..7 (rows 4*chunk..4*chunk+3).
        if (tid < 64) {
            int chunk = tid >> 3, cg = tid & 7;
            int r0 = chunk * 4, c4 = cg * 4;
            const float* ha = &S[O_H2A + c4];
            const float* hb = &S[O_H2B + c4];
            float sa[4] = {0,0,0,0}, sb[4] = {0,0,0,0};
            #pragma unroll
            for (int d = 0; d < 10; ++d) {
                float4 a = ld4(ha + (r0 + d) * H2STR);
                float4 b = ld4(hb + (r0 + d) * H2STR);
                sa[0]+=a.x; sa[1]+=a.y; sa[2]+=a.z; sa[3]+=a.w;
                sb[0]+=b.x; sb[1]+=b.y; sb[2]+=b.z; sb[3]+=b.w;
            }
            #pragma unroll
            for (int j = 0; j < 4; ++j) {
                int q = r0 + j;
                {
                    float4 a = ld4(ha + (q + 10) * H2STR);
                    float4 b = ld4(hb + (q + 10) * H2STR);
                    sa[0]+=a.x; sa[1]+=a.y; sa[2]+=a.z; sa[3]+=a.w;
                    sb[0]+=b.x; sb[1]+=b.y; sb[2]+=b.z; sb[3]+=b.w;
                }
                float4 xv = ld4(X + (size_t)(ty0 + q) * W + (tx0 + c4));
                float xs[4] = {xv.x, xv.y, xv.z, xv.w};
                #pragma unroll
                for (int k = 0; k < 4; ++k) {
                    float t = fmaf(sa[k], xs[k], sb[k]);   // (boxa*x+boxb)*121
                    float f = fmaf(-t, INV121, xs[k]);     // x - q
                    if (img == 0)      fst[j*4+k] = fabsf(f);
                    else if (img == 1) fst[j*4+k] = fmaxf(fst[j*4+k], fabsf(f));
                    else               acc += fabsf(f - fst[j*4+k]);
                }
                {
                    float4 a = ld4(ha + q * H2STR);
                    float4 b = ld4(hb + q * H2STR);
                    sa[0]-=a.x; sa[1]-=a.y; sa[2]-=a.z; sa[3]-=a.w;
                    sb[0]-=b.x; sb[1]-=b.y; sb[2]-=b.z; sb[3]-=b.w;
                }
            }
        }
    } // img loop

    // acc nonzero only in wave 0: shuffle-reduce, lane 0 writes
    #pragma unroll
    for (int off = 32; off > 0; off >>= 1) acc += __shfl_down(acc, off);
    if (tid == 0)
        partials[((blockIdx.z * NBLK_Y) + blockIdx.y) * NBLK_X + blockIdx.x] = acc;
}

__global__ __launch_bounds__(256) void sgf_final_reduce(
    const float* __restrict__ partials, float* __restrict__ out)
{
    __shared__ double sd[256];
    int tid = threadIdx.x;
    double s = 0.0;
    for (int i = tid; i < NPARTIALS; i += 256) s += (double)partials[i];
    sd[tid] = s;
    __syncthreads();
    for (int off = 128; off > 0; off >>= 1) {
        if (tid < off) sd[tid] += sd[tid + off];
        __syncthreads();
    }
    if (tid == 0) out[0] = (float)(sd[0] * (1.0 / TOTAL_ELEMS));
}

extern "C" void kernel_launch(void* const* d_in, const int* in_sizes, int n_in,
                              void* d_out, int out_size, void* d_ws, size_t ws_size,
                              hipStream_t stream) {
    const float* gen = (const float*)d_in[0];
    const float* ir  = (const float*)d_in[1];
    const float* vi  = (const float*)d_in[2];
    float* partials = (float*)d_ws;   // 6144 floats = 24 KB

    dim3 grid(NBLK_X, NBLK_Y, NPLANES);
    sgf_loss_kernel<<<grid, dim3(256), 0, stream>>>(gen, ir, vi, partials);
    sgf_final_reduce<<<1, dim3(256), 0, stream>>>(partials, (float*)d_out);
}

// Round 5
// 149.640 us; speedup vs baseline: 1.1657x; 1.1309x over previous
//
#include <hip/hip_runtime.h>
#include <hip/hip_bf16.h>

// Self-guided-filter loss, fused per 32x32 tile. v5 = v4 with the flit state in
// 16 NAMED scalar registers (P7 hand-unrolled via macro) -> no scratch spill.
// (8,3,512,512) fp32, RADIUS=5 (k=11), EPS=1e-6.

#define W 512
#define TB 32
#define H1STR 48   // h1: 52 rows, cols 0..41 valid
#define ABSTR 44   // A,B: 42 rows, cols 0..41 valid
#define H2STR 36   // h2: 42 rows, cols 0..31

#define O_H1X 0
#define O_H1Y 2496
#define O_A   4992
#define O_B   6840
#define O_H2A 0      // aliases h1x (dead after P4)
#define O_H2B 2496   // aliases h1y
#define S_FLOATS 8688  // 34,752 B -> 4 blocks/CU

#define NBLK_X 16
#define NBLK_Y 16
#define NPLANES 24
#define NPARTIALS (NBLK_X*NBLK_Y*NPLANES)
#define TOTAL_ELEMS 6291456.0
#define INV121 (1.0f/121.0f)

__device__ __forceinline__ float4 ld4(const float* p) { return *(const float4*)p; }

__global__ __launch_bounds__(256, 4) void sgf_loss_kernel(
    const float* __restrict__ gen, const float* __restrict__ ir,
    const float* __restrict__ vi, float* __restrict__ partials)
{
    __shared__ __align__(16) float S[S_FLOATS];
    const int tid = threadIdx.x;
    const int tx0 = blockIdx.x * TB;
    const int ty0 = blockIdx.y * TB;
    const size_t pbase = (size_t)blockIdx.z * (W * W);

    float acc = 0.0f;
    // flit state: 16 named scalars (lanes tid<64) -- cannot spill to scratch
    float F00, F01, F02, F03, F10, F11, F12, F13;
    float F20, F21, F22, F23, F30, F31, F32, F33;

    #pragma unroll 1
    for (int img = 0; img < 3; ++img) {
        const float* __restrict__ X =
            (img == 0 ? ir : (img == 1 ? vi : gen)) + pbase;

        __syncthreads();   // h1 region was read (as h2) in previous image's P7

        // ---- P2: global -> h1 horizontal 11-sums of x and x^2.
        // 312 tasks: 52 rows x 6 col-groups of 8. h1 col j window = img cols tx0-10+j..tx0+j.
        for (int t = tid; t < 312; t += 256) {
            int r = t / 6, cg = t - r * 6;
            int j0 = cg * 8;
            float* hx = &S[O_H1X + r * H1STR + j0];
            float* hy = &S[O_H1Y + r * H1STR + j0];
            int gy = ty0 - 10 + r;
            if ((unsigned)gy >= (unsigned)W) {
                float4 z = make_float4(0.f, 0.f, 0.f, 0.f);
                *(float4*)hx = z; *(float4*)(hx + 4) = z;
                *(float4*)hy = z; *(float4*)(hy + 4) = z;
                continue;
            }
            const float* Xr = X + (size_t)gy * W;
            int gx0 = tx0 - 12 + j0;           // 16B-aligned (tx0%32==0)
            float w[20];
            if (gx0 >= 0 && gx0 + 20 <= W) {
                const float4* p = (const float4*)(Xr + gx0);
                float4 v0 = p[0], v1 = p[1], v2 = p[2], v3 = p[3], v4 = p[4];
                w[0]=v0.x;  w[1]=v0.y;  w[2]=v0.z;  w[3]=v0.w;
                w[4]=v1.x;  w[5]=v1.y;  w[6]=v1.z;  w[7]=v1.w;
                w[8]=v2.x;  w[9]=v2.y;  w[10]=v2.z; w[11]=v2.w;
                w[12]=v3.x; w[13]=v3.y; w[14]=v3.z; w[15]=v3.w;
                w[16]=v4.x; w[17]=v4.y; w[18]=v4.z; w[19]=v4.w;
            } else {
                #pragma unroll
                for (int k = 0; k < 20; ++k) {
                    int gx = gx0 + k;
                    w[k] = ((unsigned)gx < (unsigned)W) ? Xr[gx] : 0.f;
                }
            }
            float o[8], u[8];
            float s = w[2]+w[3]+w[4]+w[5]+w[6]+w[7]+w[8]+w[9]+w[10]+w[11]+w[12];
            o[0] = s;
            #pragma unroll
            for (int k = 1; k < 8; ++k) { s += w[12+k] - w[1+k]; o[k] = s; }
            float sq[20];
            #pragma unroll
            for (int k = 2; k < 20; ++k) sq[k] = w[k] * w[k];
            float s2 = sq[2]+sq[3]+sq[4]+sq[5]+sq[6]+sq[7]+sq[8]+sq[9]+sq[10]+sq[11]+sq[12];
            u[0] = s2;
            #pragma unroll
            for (int k = 1; k < 8; ++k) { s2 += sq[12+k] - sq[1+k]; u[k] = s2; }
            *(float4*)hx       = make_float4(o[0], o[1], o[2], o[3]);
            *(float4*)(hx + 4) = make_float4(o[4], o[5], o[6], o[7]);
            *(float4*)hy       = make_float4(u[0], u[1], u[2], u[3]);
            *(float4*)(hy + 4) = make_float4(u[4], u[5], u[6], u[7]);
        }
        __syncthreads();

        // ---- P4/5: vertical 11-sums over h1 + pointwise a,b. 44 tasks (ONE wave):
        // cg 0..10 (cols 4cg..4cg+3), chunk 0..3 -> rows {0..10,11..21,22..31,32..41}.
        if (tid < 44) {
            int chunk = tid / 11, cg = tid - chunk * 11;
            int r0 = chunk * 11 - (chunk == 3 ? 1 : 0);   // 0,11,22,32
            int L  = (chunk >= 2) ? 10 : 11;
            int c4 = cg * 4;
            float mv[4];   // col mask folded into 1/121
            #pragma unroll
            for (int k = 0; k < 4; ++k) {
                int gx = tx0 - 5 + c4 + k;
                mv[k] = ((unsigned)gx < (unsigned)W) ? INV121 : 0.0f;
            }
            const float* hx = &S[O_H1X + c4];
            const float* hy = &S[O_H1Y + c4];
            float sx0=0,sx1=0,sx2=0,sx3=0, sy0=0,sy1=0,sy2=0,sy3=0;
            #pragma unroll
            for (int d = 0; d < 10; ++d) {
                float4 xn = ld4(hx + (r0 + d) * H1STR);
                float4 yn = ld4(hy + (r0 + d) * H1STR);
                sx0+=xn.x; sx1+=xn.y; sx2+=xn.z; sx3+=xn.w;
                sy0+=yn.x; sy1+=yn.y; sy2+=yn.z; sy3+=yn.w;
            }
            for (int j = 0; j < L; ++j) {
                int q = r0 + j;
                {
                    float4 xn = ld4(hx + (q + 10) * H1STR);
                    float4 yn = ld4(hy + (q + 10) * H1STR);
                    sx0+=xn.x; sx1+=xn.y; sx2+=xn.z; sx3+=xn.w;
                    sy0+=yn.x; sy1+=yn.y; sy2+=yn.z; sy3+=yn.w;
                }
                int gy = ty0 - 5 + q;
                float4 av, bv;
                if ((unsigned)gy < (unsigned)W) {
                    float sxk[4] = {sx0, sx1, sx2, sx3};
                    float syk[4] = {sy0, sy1, sy2, sy3};
                    float ao[4], bo[4];
                    #pragma unroll
                    for (int k = 0; k < 4; ++k) {
                        float mean = sxk[k] * mv[k];
                        float corr = syk[k] * mv[k];
                        float var  = fmaf(-mean, mean, corr);
                        float a_   = var * __builtin_amdgcn_rcpf(var + 1e-6f);
                        ao[k] = a_;
                        bo[k] = fmaf(-a_, mean, mean);
                    }
                    av = make_float4(ao[0], ao[1], ao[2], ao[3]);
                    bv = make_float4(bo[0], bo[1], bo[2], bo[3]);
                } else {
                    av = make_float4(0.f,0.f,0.f,0.f); bv = av;
                }
                *(float4*)&S[O_A + q * ABSTR + c4] = av;
                *(float4*)&S[O_B + q * ABSTR + c4] = bv;
                {
                    float4 xo = ld4(hx + q * H1STR);
                    float4 yo = ld4(hy + q * H1STR);
                    sx0-=xo.x; sx1-=xo.y; sx2-=xo.z; sx3-=xo.w;
                    sy0-=yo.x; sy1-=yo.y; sy2-=yo.z; sy3-=yo.w;
                }
            }
        }
        __syncthreads();

        // ---- P6: horizontal 11-sums of a,b -> h2a,h2b. 168 tasks (r 0..41, cg 0..3 -> 8 cols).
        if (tid < 168) {
            int r = tid >> 2, cg = tid & 3;
            int j0 = cg * 8;
            const float* Ap = &S[O_A + r * ABSTR + j0];
            const float* Bp = &S[O_B + r * ABSTR + j0];
            float wa[20], wb[20];
            #pragma unroll
            for (int k = 0; k < 5; ++k) {
                float4 va = ld4(Ap + 4 * k);
                wa[4*k]=va.x; wa[4*k+1]=va.y; wa[4*k+2]=va.z; wa[4*k+3]=va.w;
                float4 vb = ld4(Bp + 4 * k);
                wb[4*k]=vb.x; wb[4*k+1]=vb.y; wb[4*k+2]=vb.z; wb[4*k+3]=vb.w;
            }
            float oa[8], ob[8];
            float s = wa[0]+wa[1]+wa[2]+wa[3]+wa[4]+wa[5]+wa[6]+wa[7]+wa[8]+wa[9]+wa[10];
            oa[0] = s;
            #pragma unroll
            for (int k = 1; k < 8; ++k) { s += wa[10+k] - wa[k-1]; oa[k] = s; }
            float s2 = wb[0]+wb[1]+wb[2]+wb[3]+wb[4]+wb[5]+wb[6]+wb[7]+wb[8]+wb[9]+wb[10];
            ob[0] = s2;
            #pragma unroll
            for (int k = 1; k < 8; ++k) { s2 += wb[10+k] - wb[k-1]; ob[k] = s2; }
            float* da = &S[O_H2A + r * H2STR + j0];
            float* db = &S[O_H2B + r * H2STR + j0];
            *(float4*)da       = make_float4(oa[0], oa[1], oa[2], oa[3]);
            *(float4*)(da + 4) = make_float4(oa[4], oa[5], oa[6], oa[7]);
            *(float4*)db       = make_float4(ob[0], ob[1], ob[2], ob[3]);
            *(float4*)(db + 4) = make_float4(ob[4], ob[5], ob[6], ob[7]);
        }
        __syncthreads();

        // ---- P7/8: vertical 11-sums over h2 -> f; flit in NAMED regs.
        // 64 tasks (ONE wave): cg 0..7 (cols 4cg), chunk 0..7 (rows 4*chunk..+3).
        if (tid < 64) {
            int chunk = tid >> 3, cg = tid & 7;
            int r0 = chunk * 4, c4 = cg * 4;
            const float* ha = &S[O_H2A + c4];
            const float* hb = &S[O_H2B + c4];
            float sa0=0,sa1=0,sa2=0,sa3=0, sb0=0,sb1=0,sb2=0,sb3=0;
            #pragma unroll
            for (int d = 0; d < 10; ++d) {
                float4 a = ld4(ha + (r0 + d) * H2STR);
                float4 b = ld4(hb + (r0 + d) * H2STR);
                sa0+=a.x; sa1+=a.y; sa2+=a.z; sa3+=a.w;
                sb0+=b.x; sb1+=b.y; sb2+=b.z; sb3+=b.w;
            }

#define P7_STEP(J, G0, G1, G2, G3)                                            \
            {                                                                  \
                int q = r0 + J;                                                \
                float4 a = ld4(ha + (q + 10) * H2STR);                         \
                float4 b = ld4(hb + (q + 10) * H2STR);                         \
                sa0+=a.x; sa1+=a.y; sa2+=a.z; sa3+=a.w;                        \
                sb0+=b.x; sb1+=b.y; sb2+=b.z; sb3+=b.w;                        \
                float4 xv = ld4(X + (size_t)(ty0 + q) * W + (tx0 + c4));       \
                float t0 = fmaf(sa0, xv.x, sb0), g0 = fmaf(-t0, INV121, xv.x); \
                float t1 = fmaf(sa1, xv.y, sb1), g1 = fmaf(-t1, INV121, xv.y); \
                float t2 = fmaf(sa2, xv.z, sb2), g2 = fmaf(-t2, INV121, xv.z); \
                float t3 = fmaf(sa3, xv.w, sb3), g3 = fmaf(-t3, INV121, xv.w); \
                if (img == 0) {                                                \
                    G0 = fabsf(g0); G1 = fabsf(g1);                            \
                    G2 = fabsf(g2); G3 = fabsf(g3);                            \
                } else if (img == 1) {                                         \
                    G0 = fmaxf(G0, fabsf(g0)); G1 = fmaxf(G1, fabsf(g1));      \
                    G2 = fmaxf(G2, fabsf(g2)); G3 = fmaxf(G3, fabsf(g3));      \
                } else {                                                       \
                    acc += fabsf(g0 - G0) + fabsf(g1 - G1)                     \
                         + fabsf(g2 - G2) + fabsf(g3 - G3);                    \
                }                                                              \
                float4 ao_ = ld4(ha + q * H2STR);                              \
                float4 bo_ = ld4(hb + q * H2STR);                              \
                sa0-=ao_.x; sa1-=ao_.y; sa2-=ao_.z; sa3-=ao_.w;                \
                sb0-=bo_.x; sb1-=bo_.y; sb2-=bo_.z; sb3-=bo_.w;                \
            }

            P7_STEP(0, F00, F01, F02, F03)
            P7_STEP(1, F10, F11, F12, F13)
            P7_STEP(2, F20, F21, F22, F23)
            P7_STEP(3, F30, F31, F32, F33)
#undef P7_STEP
        }
    } // img loop

    // acc nonzero only in wave 0: shuffle-reduce, lane 0 writes
    #pragma unroll
    for (int off = 32; off > 0; off >>= 1) acc += __shfl_down(acc, off);
    if (tid == 0)
        partials[((blockIdx.z * NBLK_Y) + blockIdx.y) * NBLK_X + blockIdx.x] = acc;
}

__global__ __launch_bounds__(256) void sgf_final_reduce(
    const float* __restrict__ partials, float* __restrict__ out)
{
    __shared__ double sd[256];
    int tid = threadIdx.x;
    double s = 0.0;
    for (int i = tid; i < NPARTIALS; i += 256) s += (double)partials[i];
    sd[tid] = s;
    __syncthreads();
    for (int off = 128; off > 0; off >>= 1) {
        if (tid < off) sd[tid] += sd[tid + off];
        __syncthreads();
    }
    if (tid == 0) out[0] = (float)(sd[0] * (1.0 / TOTAL_ELEMS));
}

extern "C" void kernel_launch(void* const* d_in, const int* in_sizes, int n_in,
                              void* d_out, int out_size, void* d_ws, size_t ws_size,
                              hipStream_t stream) {
    const float* gen = (const float*)d_in[0];
    const float* ir  = (const float*)d_in[1];
    const float* vi  = (const float*)d_in[2];
    float* partials = (float*)d_ws;   // 6144 floats = 24 KB

    dim3 grid(NBLK_X, NBLK_Y, NPLANES);
    sgf_loss_kernel<<<grid, dim3(256), 0, stream>>>(gen, ir, vi, partials);
    sgf_final_reduce<<<1, dim3(256), 0, stream>>>(partials, (float*)d_out);
}